// Round 3
// baseline (356.814 us; speedup 1.0000x reference)
//
#include <hip/hip_runtime.h>

typedef __attribute__((ext_vector_type(8))) short short8;
typedef __attribute__((ext_vector_type(4))) float f32x4;

__device__ __forceinline__ unsigned short f2bf(float x) {
    union { float f; unsigned u; } v; v.f = x;
    unsigned r = v.u + 0x7FFF + ((v.u >> 16) & 1);
    return (unsigned short)(r >> 16);
}
__device__ __forceinline__ float bf2f(unsigned short h) {
    union { unsigned u; float f; } v; v.u = ((unsigned)h) << 16;
    return v.f;
}
__device__ __forceinline__ void gload_lds16(const void* g, void* l) {
    __builtin_amdgcn_global_load_lds(
        (const __attribute__((address_space(1))) unsigned*)g,
        (__attribute__((address_space(3))) unsigned*)l, 16, 0, 0);
}
#define MFMA16(a, b, c) __builtin_amdgcn_mfma_f32_16x16x32_bf16((a), (b), (c), 0, 0, 0)

// ---------------------------------------------------------------------------
// wsplit: all weight matrices -> transposed [N][K] bf16 hi/lo splits (rne).
// Segments (element counts): ew1 327680, ew2 131072, wself 196608,
// wedge 196608, mw1i 65536, mw1j 65536, w2 32768. Total 1,015,808.
// ---------------------------------------------------------------------------
#define OFF_EW1H 0
#define OFF_EW1L 327680
#define OFF_EW2H 655360
#define OFF_EW2L 786432
#define OFF_WSH  917504
#define OFF_WSL  1114112
#define OFF_WEH  1310720
#define OFF_WEL  1507328
#define OFF_M1IH 1703936
#define OFF_M1IL 1769472
#define OFF_M1JH 1835008
#define OFF_M1JL 1900544
#define OFF_W2H  1966080
#define OFF_W2L  1998848
#define SPLIT_TOTAL 2031616

__global__ __launch_bounds__(256)
void wsplit(const float* __restrict__ ew1, const float* __restrict__ ew2,
            const float* __restrict__ wself, const float* __restrict__ wedge,
            const float* __restrict__ mw1, const float* __restrict__ w2,
            short* __restrict__ o)
{
    long e = (long)blockIdx.x * 256 + threadIdx.x;
    float x; long dh, dl;
    if (e < 327680) {                       // ew1 [640][512] -> [512][640]
        int k = e >> 9, n = e & 511;
        x = ew1[e]; dh = OFF_EW1H + (long)n * 640 + k; dl = OFF_EW1L + (long)n * 640 + k;
    } else if ((e -= 327680) < 131072) {    // ew2 [512][256] -> [256][512]
        int k = e >> 8, n = e & 255;
        x = ew2[e]; dh = OFF_EW2H + (long)n * 512 + k; dl = OFF_EW2L + (long)n * 512 + k;
    } else if ((e -= 131072) < 196608) {    // wself [3][256][256] -> [3][256][256]T
        int lyr = e >> 16, r = e & 65535, k = r >> 8, n = r & 255;
        x = wself[e]; long d = (long)lyr * 65536 + n * 256 + k;
        dh = OFF_WSH + d; dl = OFF_WSL + d;
    } else if ((e -= 196608) < 196608) {    // wedge
        int lyr = e >> 16, r = e & 65535, k = r >> 8, n = r & 255;
        x = wedge[e]; long d = (long)lyr * 65536 + n * 256 + k;
        dh = OFF_WEH + d; dl = OFF_WEL + d;
    } else if ((e -= 196608) < 65536) {     // mw1 rows 0..255 -> [256][256]T
        int k = e >> 8, n = e & 255;
        x = mw1[e]; dh = OFF_M1IH + (long)n * 256 + k; dl = OFF_M1IL + (long)n * 256 + k;
    } else if ((e -= 65536) < 65536) {      // mw1 rows 256..511
        int k = e >> 8, n = e & 255;
        x = mw1[65536 + e]; dh = OFF_M1JH + (long)n * 256 + k; dl = OFF_M1JL + (long)n * 256 + k;
    } else if ((e -= 65536) < 32768) {      // w2 [256][128] -> [128][256]
        int k = e >> 7, n = e & 127;
        x = w2[e]; dh = OFF_W2H + (long)n * 256 + k; dl = OFF_W2L + (long)n * 256 + k;
    } else return;
    unsigned short h = f2bf(x);
    unsigned short lo = f2bf(x - bf2f(h));
    o[dh] = (short)h; o[dl] = (short)lo;
}

// ---------------------------------------------------------------------------
// Generic MFMA GEMM: C = act(A @ B + bias), A fp32 [M][K] (split in-kernel),
// B pre-split transposed [N][K] bf16 hi/lo, 3-pass. BM=BN=64, BK=32, 4 waves.
// Dual-B via nxHalf.
// ---------------------------------------------------------------------------
template<bool RELU>
__global__ __launch_bounds__(256, 4)
void gemm_mfma(const float* __restrict__ A,
               const short* __restrict__ BTh0, const short* __restrict__ BTl0,
               const float* __restrict__ bias0, float* __restrict__ C0,
               const short* __restrict__ BTh1, const short* __restrict__ BTl1,
               const float* __restrict__ bias1, float* __restrict__ C1,
               int M, int N, int K, int nxHalf)
{
    int bx = blockIdx.x;
    const short* BTh = BTh0; const short* BTl = BTl0;
    const float* bias = bias0; float* C = C0;
    if (nxHalf && bx >= nxHalf) { bx -= nxHalf; BTh = BTh1; BTl = BTl1; bias = bias1; C = C1; }
    const int m0 = blockIdx.y * 64, n0 = bx * 64;
    const int tid = threadIdx.x, l = tid & 63;
    const int wid = tid >> 6;
    const int wm0 = (wid & 1) * 32, wn0 = (wid >> 1) * 32;
    const int g = l >> 4, ln = l & 15;

    __shared__ __align__(16) float As[64 * 32];
    __shared__ __align__(16) short Ah[64 * 32];
    __shared__ __align__(16) short Al[64 * 32];

    f32x4 acc[2][2] = {};

    {   // prologue: stage A tile 0 (8 KB via 2x global_load_lds per thread)
        int row = tid >> 3, q = tid & 7;
        gload_lds16(&A[(long)(m0 + row) * K + q * 4], (char*)As + tid * 16);
        gload_lds16(&A[(long)(m0 + 32 + row) * K + q * 4], (char*)As + 4096 + tid * 16);
    }
    __syncthreads();

    const int ktiles = K >> 5;
    for (int kt = 0; kt < ktiles; ++kt) {
        const int k0 = kt << 5;
        {   // split As -> Ah/Al (trunc hi, trunc lo), swizzled
            int row = tid >> 2, kb = (tid & 3) << 3;
            const float* src = &As[row * 32 + kb];
            int base = row * 64 + kb * 2;
            int swz = (row & 7) << 4;
            char* ph = (char*)Ah; char* pl = (char*)Al;
#pragma unroll
            for (int q = 0; q < 2; ++q) {
                float4 v = *(const float4*)(src + q * 4);
                float xs[4] = {v.x, v.y, v.z, v.w};
                unsigned hw[4], lw[4];
#pragma unroll
                for (int e2 = 0; e2 < 4; ++e2) {
                    union { float f; unsigned u; } uu; uu.f = xs[e2];
                    unsigned hbits = uu.u & 0xFFFF0000u;
                    union { unsigned u; float f; } hh; hh.u = hbits;
                    union { float f; unsigned u; } ll; ll.f = xs[e2] - hh.f;
                    hw[e2] = hbits >> 16; lw[e2] = ll.u >> 16;
                }
                int b2 = base + q * 8;
                *(unsigned*)(ph + ((b2    ) ^ swz)) = hw[0] | (hw[1] << 16);
                *(unsigned*)(ph + ((b2 + 4) ^ swz)) = hw[2] | (hw[3] << 16);
                *(unsigned*)(pl + ((b2    ) ^ swz)) = lw[0] | (lw[1] << 16);
                *(unsigned*)(pl + ((b2 + 4) ^ swz)) = lw[2] | (lw[3] << 16);
            }
        }
        __syncthreads();   // split visible

        short8 bh[2], bl[2], ah[2], al[2];
#pragma unroll
        for (int nf = 0; nf < 2; ++nf) {
            int col = n0 + wn0 + nf * 16 + ln;
            long bo = (long)col * K + k0 + g * 8;
            bh[nf] = *(const short8*)(BTh + bo);
            bl[nf] = *(const short8*)(BTl + bo);
        }
#pragma unroll
        for (int mf = 0; mf < 2; ++mf) {
            int row = wm0 + mf * 16 + ln;
            int off = (row * 64 + g * 16) ^ ((row & 7) << 4);
            ah[mf] = *(const short8*)((const char*)Ah + off);
            al[mf] = *(const short8*)((const char*)Al + off);
        }
#pragma unroll
        for (int mf = 0; mf < 2; ++mf)
#pragma unroll
            for (int nf = 0; nf < 2; ++nf) {
                acc[mf][nf] = MFMA16(ah[mf], bh[nf], acc[mf][nf]);
                acc[mf][nf] = MFMA16(ah[mf], bl[nf], acc[mf][nf]);
                acc[mf][nf] = MFMA16(al[mf], bh[nf], acc[mf][nf]);
            }
        if (kt + 1 < ktiles) {   // stage next A tile
            int row = tid >> 3, q = tid & 7;
            gload_lds16(&A[(long)(m0 + row) * K + k0 + 32 + q * 4], (char*)As + tid * 16);
            gload_lds16(&A[(long)(m0 + 32 + row) * K + k0 + 32 + q * 4], (char*)As + 4096 + tid * 16);
        }
        __syncthreads();   // stage drained; Ah/Al reads done before next split
    }

#pragma unroll
    for (int mf = 0; mf < 2; ++mf)
#pragma unroll
        for (int nf = 0; nf < 2; ++nf) {
            int colb = n0 + wn0 + nf * 16 + ln;
            float bv = bias ? bias[colb] : 0.f;
#pragma unroll
            for (int r = 0; r < 4; ++r) {
                int row = m0 + wm0 + mf * 16 + g * 4 + r;
                float v = acc[mf][nf][r] + bv;
                if (RELU) v = fmaxf(v, 0.f);
                C[(long)row * N + colb] = v;
            }
        }
}

// ---------------------------------------------------------------------------
// Dense fp32 GEMM (kept for the bmm): BM=32 BN=64 BK=32, batched.
// ---------------------------------------------------------------------------
__global__ __launch_bounds__(256)
void gemm32(const float* __restrict__ A, const float* __restrict__ B,
            float* __restrict__ C, int M, int N, int K, int aB, int bB, int cB)
{
    A += (long)blockIdx.z * aB;
    B += (long)blockIdx.z * bB;
    C += (long)blockIdx.z * cB;
    const int m0 = blockIdx.y * 32, n0 = blockIdx.x * 64;
    __shared__ __align__(16) float As2[32][36];
    __shared__ __align__(16) float Bs2[32][68];
    const int tid = threadIdx.x;
    const int tx = tid & 15, ty = tid >> 4;
    float acc[2][4] = {};
    for (int k0 = 0; k0 < K; k0 += 32) {
        {
            int row = tid >> 3, kq = (tid & 7) << 2;
            float4 v = *(const float4*)&A[(long)(m0 + row) * K + k0 + kq];
            As2[kq + 0][row] = v.x; As2[kq + 1][row] = v.y;
            As2[kq + 2][row] = v.z; As2[kq + 3][row] = v.w;
        }
#pragma unroll
        for (int q = 0; q < 2; ++q) {
            int f = tid * 2 + q;
            int kk = f >> 4, nn = (f & 15) << 2;
            *(float4*)&Bs2[kk][nn] = *(const float4*)&B[(long)(k0 + kk) * N + n0 + nn];
        }
        __syncthreads();
#pragma unroll
        for (int k = 0; k < 32; ++k) {
            float2 a2 = *(const float2*)&As2[k][ty * 2];
            float4 b4 = *(const float4*)&Bs2[k][tx * 4];
            acc[0][0] += a2.x * b4.x; acc[0][1] += a2.x * b4.y;
            acc[0][2] += a2.x * b4.z; acc[0][3] += a2.x * b4.w;
            acc[1][0] += a2.y * b4.x; acc[1][1] += a2.y * b4.y;
            acc[1][2] += a2.y * b4.z; acc[1][3] += a2.y * b4.w;
        }
        __syncthreads();
    }
#pragma unroll
    for (int i = 0; i < 2; ++i) {
        int m = m0 + ty * 2 + i;
#pragma unroll
        for (int j = 0; j < 4; ++j)
            C[(long)m * N + n0 + tx * 4 + j] = acc[i][j];
    }
}

// ---------------------------------------------------------------------------
// h = LayerNorm(relu(a + b)) * g + bb — one block per row of 256
// ---------------------------------------------------------------------------
__global__ __launch_bounds__(256)
void add_relu_ln(const float* __restrict__ a, const float* __restrict__ b,
                 const float* __restrict__ g, const float* __restrict__ bb,
                 float* __restrict__ o)
{
    const int row = blockIdx.x, t = threadIdx.x;
    const long idx = (long)row * 256 + t;
    float x = fmaxf(a[idx] + b[idx], 0.f);
    float s = x, s2 = x * x;
#pragma unroll
    for (int off = 1; off < 64; off <<= 1) {
        s  += __shfl_xor(s,  off, 64);
        s2 += __shfl_xor(s2, off, 64);
    }
    __shared__ float ws1[4], ws2[4];
    const int wid = t >> 6, lane = t & 63;
    if (lane == 0) { ws1[wid] = s; ws2[wid] = s2; }
    __syncthreads();
    s  = ws1[0] + ws1[1] + ws1[2] + ws1[3];
    s2 = ws2[0] + ws2[1] + ws2[2] + ws2[3];
    const float mu  = s * (1.f / 256.f);
    const float var = s2 * (1.f / 256.f) - mu * mu;
    o[idx] = (x - mu) * rsqrtf(var + 1e-5f) * g[t] + bb[t];
}

// ---------------------------------------------------------------------------
// Fused pairwise scorer, MFMA 3-pass, 2-barrier double-buffered schedule.
// Block: 128 pairs (2 i x 64 j) x N=128, 4 waves (2M x 2N).
// ---------------------------------------------------------------------------
#define BUILD_P(KT, BUF)                                                        \
    {                                                                           \
        const int p = tid >> 1, kb = (tid & 1) << 4;                            \
        const int ii = p >> 6, jj = p & 63;                                     \
        const float bw = bpv[p];                                                \
        const int k0b = (KT) * 32;                                              \
        const int swz = (p & 7) << 4;                                           \
        char* ph = (char*)&Ph[BUF][0];                                          \
        char* pl = (char*)&Pl[BUF][0];                                          \
        _Pragma("unroll")                                                       \
        for (int q = 0; q < 4; ++q) {                                           \
            float4 hv = *(const float4*)&hjs[jj * 32 + kb + q * 4];             \
            float4 iv = *(const float4*)&his[ii][k0b + kb + q * 4];             \
            float4 cv = *(const float4*)&cs[k0b + kb + q * 4];                  \
            float4 bv = *(const float4*)&b1s[k0b + kb + q * 4];                 \
            float xs[4];                                                        \
            xs[0] = fmaxf(iv.x + hv.x + bw * cv.x + bv.x, 0.f);                 \
            xs[1] = fmaxf(iv.y + hv.y + bw * cv.y + bv.y, 0.f);                 \
            xs[2] = fmaxf(iv.z + hv.z + bw * cv.z + bv.z, 0.f);                 \
            xs[3] = fmaxf(iv.w + hv.w + bw * cv.w + bv.w, 0.f);                 \
            unsigned hw[4], lw[4];                                              \
            _Pragma("unroll")                                                   \
            for (int e2 = 0; e2 < 4; ++e2) {                                    \
                union { float f; unsigned u; } uu; uu.f = xs[e2];               \
                unsigned hbits = uu.u & 0xFFFF0000u;                            \
                union { unsigned u; float f; } hh; hh.u = hbits;                \
                union { float f; unsigned u; } llu; llu.f = xs[e2] - hh.f;      \
                hw[e2] = hbits >> 16; lw[e2] = llu.u >> 16;                     \
            }                                                                   \
            int baseb = p * 64 + (kb + q * 4) * 2;                              \
            *(unsigned*)(ph + ((baseb    ) ^ swz)) = hw[0] | (hw[1] << 16);     \
            *(unsigned*)(ph + ((baseb + 4) ^ swz)) = hw[2] | (hw[3] << 16);     \
            *(unsigned*)(pl + ((baseb    ) ^ swz)) = lw[0] | (lw[1] << 16);     \
            *(unsigned*)(pl + ((baseb + 4) ^ swz)) = lw[2] | (lw[3] << 16);     \
        }                                                                       \
    }

#define LOAD_B(K0)                                                              \
    _Pragma("unroll")                                                           \
    for (int nf = 0; nf < 4; ++nf) {                                            \
        int col = wn0 + nf * 16 + ln;                                           \
        long bo = (long)col * 256 + (K0) + g * 8;                               \
        bh[nf] = *(const short8*)(w2th + bo);                                   \
        bl[nf] = *(const short8*)(w2tl + bo);                                   \
    }

__global__ __launch_bounds__(256, 3)
void pairwise_mfma(const float* __restrict__ hia, const float* __restrict__ hja,
                   const float* __restrict__ bp,
                   const float* __restrict__ c, const float* __restrict__ b1,
                   const short* __restrict__ w2th, const short* __restrict__ w2tl,
                   const float* __restrict__ b2, const float* __restrict__ w3,
                   const float* __restrict__ b3, float* __restrict__ out)
{
    const int b = blockIdx.z, ib0 = blockIdx.y * 2, jb = blockIdx.x;
    const int tid = threadIdx.x, l = tid & 63, wid = tid >> 6;
    const int wm0 = (wid & 1) * 64, wn0 = (wid >> 1) * 64;
    const int g = l >> 4, ln = l & 15;

    __shared__ __align__(16) short Ph[2][128 * 32];
    __shared__ __align__(16) short Pl[2][128 * 32];
    __shared__ __align__(16) float hjs[64 * 32];
    __shared__ __align__(16) float his[2][256];
    __shared__ __align__(16) float cs[256];
    __shared__ __align__(16) float b1s[256];
    __shared__ float bpv[128];
    __shared__ float red[128][2];

    // persistent staging: bpv, his (2 full rows), cs, b1s
    if (tid < 128) {
        int i = ib0 + (tid >> 6), j = jb * 64 + (tid & 63);
        bpv[tid] = bp[((long)(b * 256 + i)) * 256 + j];
        int r = tid >> 6, kq = (tid & 63) << 2;
        *(float4*)&his[r][kq] = *(const float4*)&hia[((long)(b * 256 + ib0 + r)) * 256 + kq];
    } else if (tid < 192) {
        int kq = (tid - 128) << 2;
        *(float4*)&cs[kq] = *(const float4*)&c[kq];
    } else {
        int kq = (tid - 192) << 2;
        *(float4*)&b1s[kq] = *(const float4*)&b1[kq];
    }
    {   // stage hjs tile 0
        int row = tid >> 3, q = tid & 7;
        long gbase = ((long)(b * 256 + jb * 64 + row)) * 256 + q * 4;
        gload_lds16(&hja[gbase], (char*)hjs + tid * 16);
        gload_lds16(&hja[gbase + 32 * 256], (char*)hjs + 4096 + tid * 16);
    }
    __syncthreads();

    short8 bh[4], bl[4];
    LOAD_B(0);
    BUILD_P(0, 0);
    __syncthreads();

    f32x4 acc[4][4] = {};

    for (int kt = 0; kt < 8; ++kt) {
        const int cur = kt & 1;
        if (kt < 7) {   // stage hjs(t+1)
            int row = tid >> 3, q = tid & 7;
            long gbase = ((long)(b * 256 + jb * 64 + row)) * 256 + (kt + 1) * 32 + q * 4;
            gload_lds16(&hja[gbase], (char*)hjs + tid * 16);
            gload_lds16(&hja[gbase + 32 * 256], (char*)hjs + 4096 + tid * 16);
        }
        short8 ah[4], al[4];
#pragma unroll
        for (int mf = 0; mf < 4; ++mf) {
            int row = wm0 + mf * 16 + ln;
            int off = (row * 64 + g * 16) ^ ((row & 7) << 4);
            ah[mf] = *(const short8*)((const char*)&Ph[cur][0] + off);
            al[mf] = *(const short8*)((const char*)&Pl[cur][0] + off);
        }
#pragma unroll
        for (int mf = 0; mf < 4; ++mf)
#pragma unroll
            for (int nf = 0; nf < 4; ++nf) {
                acc[mf][nf] = MFMA16(ah[mf], bh[nf], acc[mf][nf]);
                acc[mf][nf] = MFMA16(ah[mf], bl[nf], acc[mf][nf]);
                acc[mf][nf] = MFMA16(al[mf], bh[nf], acc[mf][nf]);
            }
        __syncthreads();   // hjs(t+1) visible; all P[cur] reads done
        if (kt < 7) {
            LOAD_B((kt + 1) * 32);   // B prefetch hides under build
            BUILD_P(kt + 1, cur ^ 1);
        }
        __syncthreads();   // P(t+1) visible
    }

    // epilogue: relu(+b2) dot w3, 16-lane shfl reduce, cross-wave via LDS
    float b2v[4], w3v[4];
#pragma unroll
    for (int nf = 0; nf < 4; ++nf) {
        int col = wn0 + nf * 16 + ln;
        b2v[nf] = b2[col];
        w3v[nf] = w3[col];
    }
#pragma unroll
    for (int mf = 0; mf < 4; ++mf) {
#pragma unroll
        for (int r = 0; r < 4; ++r) {
            float s = 0.f;
#pragma unroll
            for (int nf = 0; nf < 4; ++nf)
                s += fmaxf(acc[mf][nf][r] + b2v[nf], 0.f) * w3v[nf];
            s += __shfl_xor(s, 1, 64);
            s += __shfl_xor(s, 2, 64);
            s += __shfl_xor(s, 4, 64);
            s += __shfl_xor(s, 8, 64);
            if (ln == 0)
                red[wm0 + mf * 16 + g * 4 + r][wid >> 1] = s;
        }
    }
    __syncthreads();
    if (tid < 128) {
        int i = ib0 + (tid >> 6), j = jb * 64 + (tid & 63);
        out[((long)(b * 256 + i)) * 256 + j] = red[tid][0] + red[tid][1] + b3[0];
    }
}

// ---------------------------------------------------------------------------
extern "C" void kernel_launch(void* const* d_in, const int* in_sizes, int n_in,
                              void* d_out, int out_size, void* d_ws, size_t ws_size,
                              hipStream_t stream)
{
    const float* emb   = (const float*)d_in[0];
    const float* bp    = (const float*)d_in[1];
    const float* ew1   = (const float*)d_in[3];
    const float* eb1   = (const float*)d_in[4];
    const float* ew2   = (const float*)d_in[5];
    const float* eb2   = (const float*)d_in[6];
    const float* wself = (const float*)d_in[7];
    const float* bself = (const float*)d_in[8];
    const float* wedge = (const float*)d_in[9];
    const float* bedge = (const float*)d_in[10];
    const float* lng   = (const float*)d_in[11];
    const float* lnb   = (const float*)d_in[12];
    const float* mw1   = (const float*)d_in[13];
    const float* mb1   = (const float*)d_in[14];
    const float* mw2   = (const float*)d_in[15];
    const float* mb2   = (const float*)d_in[16];
    const float* mw3   = (const float*)d_in[17];
    const float* mb3   = (const float*)d_in[18];
    float* out = (float*)d_out;

    float* ws = (float*)d_ws;
    float* h1 = ws;               // 524288
    float* h  = h1 + 524288;      // 262144
    float* sf = h  + 262144;      // 262144
    float* eg = sf + 262144;      // 262144
    float* ng = eg + 262144;      // 262144
    float* hi = ng + 262144;      // 262144
    float* hj = hi + 262144;      // 262144  (floats total 2,097,152)
    short* sb = (short*)(hj + 262144);   // split region, SPLIT_TOTAL shorts

    dim3 blk(256);

    // weight splits
    wsplit<<<dim3(3968), blk, 0, stream>>>(ew1, ew2, wself, wedge, mw1, mw2, sb);

    // FeatureEncoder
    gemm_mfma<true ><<<dim3(8, 16), blk, 0, stream>>>(emb,
        sb + OFF_EW1H, sb + OFF_EW1L, eb1, h1,
        nullptr, nullptr, nullptr, nullptr, 1024, 512, 640, 0);
    gemm_mfma<false><<<dim3(4, 16), blk, 0, stream>>>(h1,
        sb + OFF_EW2H, sb + OFF_EW2L, eb2, h,
        nullptr, nullptr, nullptr, nullptr, 1024, 256, 512, 0);

    // GCN layers
    for (int lyr = 0; lyr < 3; ++lyr) {
        gemm_mfma<false><<<dim3(8, 16), blk, 0, stream>>>(h,
            sb + OFF_WSH + lyr * 65536, sb + OFF_WSL + lyr * 65536, bself + lyr * 256, sf,
            sb + OFF_WEH + lyr * 65536, sb + OFF_WEL + lyr * 65536, bedge + lyr * 256, eg,
            1024, 256, 256, 4);
        gemm32<<<dim3(4, 8, 4), blk, 0, stream>>>(bp, eg, ng, 256, 256, 256,
                                                  65536, 65536, 65536);
        add_relu_ln<<<dim3(1024), blk, 0, stream>>>(sf, ng,
            lng + lyr * 256, lnb + lyr * 256, h);
    }

    // hi / hj partial products (dual, shared A)
    gemm_mfma<false><<<dim3(8, 16), blk, 0, stream>>>(h,
        sb + OFF_M1IH, sb + OFF_M1IL, nullptr, hi,
        sb + OFF_M1JH, sb + OFF_M1JL, nullptr, hj,
        1024, 256, 256, 4);

    // Fused pairwise MFMA scorer
    pairwise_mfma<<<dim3(4, 128, 4), blk, 0, stream>>>(hi, hj, bp,
        mw1 + 131072, mb1, sb + OFF_W2H, sb + OFF_W2L, mb2, mw3, mb3, out);
}